// Round 4
// baseline (434.513 us; speedup 1.0000x reference)
//
#include <hip/hip_runtime.h>
#include <hip/hip_cooperative_groups.h>

#define BS 256
#define NB 1024   // 4 blocks/CU x 256 CUs — co-resident under __launch_bounds__(256,4)

typedef float vfloat4 __attribute__((ext_vector_type(4)));

// One cooperative kernel, three phases:
//  P1: colpart[b*32+j] = block-partial of sum_i w_i*x[i][j]; wpart[b] = 8*sum w_i
//      (w counted once per float4 chunk = 8x per row; *0.125 later, exact).
//  grid.sync (+device fences for cross-XCD L2 visibility of partials)
//  P2: EVERY block redundantly reduces all partials (132 KB, L2/L3 broadcast)
//      and computes r = W_out @ relu(W_in @ avg) into LDS.
//  P3: out = x + r (x re-read, L3-warm; NT stores for out).
__global__ void __launch_bounds__(BS, 4) fused_kernel(
    const float* __restrict__ x, const float* __restrict__ w,
    const float* __restrict__ W_in, const float* __restrict__ W_out,
    float* __restrict__ out, float* __restrict__ colpart,
    float* __restrict__ wpart, long long total4) {
  const int tid = threadIdx.x;
  const long long stride2 = (long long)gridDim.x * (2 * BS);
  const long long c0 = (long long)blockIdx.x * (2 * BS) + tid;
  const vfloat4* x4 = (const vfloat4*)x;

  __shared__ vfloat4 sacc[BS];
  __shared__ float   sw[BS];
  __shared__ float   avg[32];
  __shared__ float   h[128];
  __shared__ float   rsh[32];

  // ---- Phase 1: weighted column reduction over this block's chunks ----
  {
    vfloat4 a0 = (vfloat4)(0.f), a1 = (vfloat4)(0.f);
    float w0 = 0.f, w1 = 0.f;
    long long c = c0;
    for (; c + BS < total4; c += stride2) {
      const float wi0 = w[(int)(c >> 3)];
      const float wi1 = w[(int)((c + BS) >> 3)];
      a0 += wi0 * x4[c];
      a1 += wi1 * x4[c + BS];
      w0 += wi0; w1 += wi1;
    }
    if (c < total4) {
      const float wi = w[(int)(c >> 3)];
      a0 += wi * x4[c];
      w0 += wi;
    }
    a0 += a1; w0 += w1;
    sacc[tid] = a0;
    sw[tid] = w0;
  }
  __syncthreads();
  for (int s = BS / 2; s >= 8; s >>= 1) {  // keep column groups (tid&7) apart
    if (tid < s) {
      sacc[tid] += sacc[tid + s];
      sw[tid] += sw[tid + s];
    }
    __syncthreads();
  }
  if (tid < 8) {
    ((vfloat4*)(colpart + (long long)blockIdx.x * 32))[tid] = sacc[tid];
  }
  if (tid == 0) {
    wpart[blockIdx.x] = sw[0] + sw[1] + sw[2] + sw[3] +
                        sw[4] + sw[5] + sw[6] + sw[7];
  }
  __threadfence();                         // agent-scope release (L2 writeback)
  cooperative_groups::this_grid().sync();  // all partials written
  __threadfence();                         // agent-scope acquire (L2 inv)

  // ---- Phase 2: every block redundantly reduces all partials -> r in LDS ----
  {
    const vfloat4* cp4 = (const vfloat4*)colpart;
    vfloat4 acc = (vfloat4)(0.f);
    for (int cb = tid; cb < NB * 8; cb += BS) acc += cp4[cb];  // quad = tid&7
    sacc[tid] = acc;
    const vfloat4* wp4 = (const vfloat4*)wpart;
    float s = 0.f;
    for (int cb = tid; cb < NB / 4; cb += BS) {
      vfloat4 v = wp4[cb];
      s += v.x + v.y + v.z + v.w;
    }
    sw[tid] = s;
  }
  __syncthreads();
  for (int s = BS / 2; s >= 8; s >>= 1) {
    if (tid < s) {
      sacc[tid] += sacc[tid + s];
      sw[tid] += sw[tid + s];
    }
    __syncthreads();
  }
  if (tid == 0) {
    // wpart counted each w 8x (once per chunk) -> *0.125 (exact)
    sw[0] = (sw[0] + sw[1] + sw[2] + sw[3] +
             sw[4] + sw[5] + sw[6] + sw[7]) * 0.125f;
  }
  __syncthreads();
  if (tid < 32) {
    const float* sflat = (const float*)sacc;  // column j = sacc[j>>2][j&3]
    avg[tid] = sflat[tid] / sw[0];
  }
  __syncthreads();
  if (tid < 128) {
    float a = 0.f;
    for (int k = 0; k < 32; ++k) a = fmaf(W_in[tid * 32 + k], avg[k], a);
    h[tid] = fmaxf(a, 0.f);
  }
  __syncthreads();
  if (tid < 32) {
    float r = 0.f;
    for (int k = 0; k < 128; ++k) r = fmaf(W_out[tid * 128 + k], h[k], r);
    rsh[tid] = r;
  }
  __syncthreads();

  // ---- Phase 3: out = x + r (x L3-warm; NT stores) ----
  {
    const vfloat4 rr = ((const vfloat4*)rsh)[tid & 7];
    vfloat4* o4 = (vfloat4*)out;
    long long c = c0;
    for (; c + BS < total4; c += stride2) {
      vfloat4 v0 = x4[c] + rr;
      vfloat4 v1 = x4[c + BS] + rr;
      __builtin_nontemporal_store(v0, &o4[c]);
      __builtin_nontemporal_store(v1, &o4[c + BS]);
    }
    if (c < total4) {
      vfloat4 v = x4[c] + rr;
      __builtin_nontemporal_store(v, &o4[c]);
    }
  }
}

extern "C" void kernel_launch(void* const* d_in, const int* in_sizes, int n_in,
                              void* d_out, int out_size, void* d_ws, size_t ws_size,
                              hipStream_t stream) {
  const float* x     = (const float*)d_in[0];
  const float* w     = (const float*)d_in[1];
  const float* W_in  = (const float*)d_in[2];
  const float* W_out = (const float*)d_in[3];
  float* out = (float*)d_out;

  const long long N = (long long)in_sizes[0] / 32;
  long long total4 = N * 8;  // float4 chunks (32 floats/row)

  // workspace: colpart[NB*32] | wpart[NB]  (~136 KB; ws is far larger)
  float* colpart = (float*)d_ws;
  float* wpart   = colpart + (size_t)NB * 32;

  void* args[] = {(void*)&x, (void*)&w, (void*)&W_in, (void*)&W_out,
                  (void*)&out, (void*)&colpart, (void*)&wpart, (void*)&total4};
  hipLaunchCooperativeKernel((const void*)fused_kernel, dim3(NB), dim3(BS),
                             args, 0, stream);
}